// Round 7
// baseline (42.733 us; speedup 1.0000x reference)
//
#include <hip/hip_runtime.h>

#define S_LEN 4096
#define DIM   64
#define HALF  50
#define RB    128           // query rows per inner tile; block does 2 tiles (256 rows)
#define WQ    16            // query rows per wave (8 waves)
#define THREADS 512
#define KCAP  256           // staged keys per tile: kstart 32-aligned, span <= 242
#define SCALE 0.125f

typedef __attribute__((ext_vector_type(8))) short bf16x8;
typedef __attribute__((ext_vector_type(4))) float f32x4;

__device__ __forceinline__ unsigned int bf16_rne(float f) {
    unsigned int u = __float_as_uint(f);
    return (u + 0x7fffu + ((u >> 16) & 1u)) >> 16;
}
__device__ __forceinline__ unsigned int pk2(float lo, float hi) {
    return bf16_rne(lo) | (bf16_rne(hi) << 16);
}
__device__ __forceinline__ bf16x8 cvt8(float4 a, float4 b) {
    uint4 t = make_uint4(pk2(a.x, a.y), pk2(a.z, a.w), pk2(b.x, b.y), pk2(b.z, b.w));
    return __builtin_bit_cast(bf16x8, t);
}

// inner compute for one 128-row tile (round-3-verified loop), reads staged buffers
__device__ __forceinline__ void attend_store(
    const unsigned short* __restrict__ Ksb, const unsigned short* __restrict__ Vsb,
    unsigned short* __restrict__ Pw, const bf16x8* qf,
    int kstart, int kend, int qlo, int g, int cc, float* __restrict__ Og)
{
    f32x4 oacc[4] = {};
    float denom = 0.f;

    int lo = (qlo >= HALF) ? (qlo - HALF) : 0;
    lo = max(kstart, lo & ~31);
    const int t0 = (lo - kstart) >> 5;
    const int hi = min(kend, qlo + WQ - 1 + HALF + 1);
    const int t1 = (hi - kstart + 31) >> 5;

    for (int st = t0; st < t1; ++st) {
        const int kb32 = st << 5;

        // swapped QK^T: S^T[key][q]
        f32x4 sacc[2] = {};
        #pragma unroll
        for (int ds = 0; ds < 2; ++ds) {
            #pragma unroll
            for (int kt = 0; kt < 2; ++kt) {
                const int krow = kb32 + kt * 16 + cc;
                const int sl   = (ds * 4 + g) ^ (krow & 7);
                const bf16x8 kfr = *(const bf16x8*)(Ksb + krow * 64 + sl * 8);
                sacc[kt] = __builtin_amdgcn_mfma_f32_16x16x32_bf16(kfr, qf[ds], sacc[kt], 0, 0, 0);
            }
        }

        // mask + exp + P layout shuffle (per-wave LDS, wave-internal sync only)
        const int q = qlo + cc;
        #pragma unroll
        for (int kt = 0; kt < 2; ++kt) {
            float w4[4];
            const int keyb = kstart + kb32 + kt * 16 + g * 4;
            #pragma unroll
            for (int r = 0; r < 4; ++r) {
                const int key = keyb + r;
                const float e = __expf(fminf(sacc[kt][r], 60.f));
                const int dd  = key - q;
                const bool ok = (dd >= -HALF) && (dd <= HALF) && (key < S_LEN);
                w4[r] = ok ? e : 0.f;
                denom += w4[r];
            }
            *(uint2*)(Pw + cc * 40 + kt * 16 + g * 4) =
                make_uint2(pk2(w4[0], w4[1]), pk2(w4[2], w4[3]));
        }
        const bf16x8 pf = *(const bf16x8*)(Pw + cc * 40 + g * 8);

        // PV: O^T += V^T x P
        #pragma unroll
        for (int dt = 0; dt < 4; ++dt) {
            const int d  = dt * 16 + cc;
            const int sl = ((kb32 >> 3) + g) ^ (d & 7) ^ ((d >> 3) & 7);
            const bf16x8 vf = *(const bf16x8*)(Vsb + d * KCAP + sl * 8);
            oacc[dt] = __builtin_amdgcn_mfma_f32_16x16x32_bf16(vf, pf, oacc[dt], 0, 0, 0);
        }
    }

    denom += __shfl_xor(denom, 16);
    denom += __shfl_xor(denom, 32);
    const float rinv = 1.f / denom;
    float* dst = Og + (size_t)(qlo + cc) * DIM;
    #pragma unroll
    for (int dt = 0; dt < 4; ++dt) {
        const f32x4 o = oacc[dt];
        *(float4*)(dst + dt * 16 + g * 4) =
            make_float4(o[0] * rinv, o[1] * rinv, o[2] * rinv, o[3] * rinv);
    }
}

// LDS: Ks[2] 256x64 bf16 (32KB each), Vs[2] 64x256 bf16 transposed (32KB each),
//      Ps 8 waves x 16q x 40k scratch (10KB) -> 138KB, 1 block/CU.
// Pipeline: stage(t0); bar; issue loads(t1); compute(t0); write(t1); bar; compute(t1).
__global__ __launch_bounds__(THREADS)
void lattn_mfma(const float* __restrict__ Q, const float* __restrict__ K,
                const float* __restrict__ V, float* __restrict__ O) {
    __shared__ unsigned short Ks[2][KCAP * 64];
    __shared__ unsigned short Vs[2][DIM * KCAP];
    __shared__ unsigned short Ps[8 * 16 * 40];

    // bijective XCD swizzle: consecutive super-tiles (overlapping halos) share an XCD L2
    const int nwg = gridDim.x;                 // 256
    const int cpx = nwg >> 3;
    const int bid = blockIdx.x;
    const int logical = (bid & 7) * cpx + (bid >> 3);
    const int bh = logical >> 4;               // 16 super-tiles per bh
    const int R0 = (logical & 15) * (2 * RB);  // 256-row super-tile

    const size_t base = (size_t)bh * (S_LEN * DIM);
    const float* Qg = Q + base;
    const float* Kg = K + base;
    const float* Vg = V + base;
    float*       Og = O + base;

    const int u = threadIdx.x;
    const int lane = u & 63;
    const int wv_  = u >> 6;
    const int g  = lane >> 4;
    const int cc = lane & 15;

    const int r0a = R0, r0b = R0 + RB;
    const int ksa = (r0a >= HALF) ? ((r0a - HALF) & ~31) : 0;
    const int kea = min(S_LEN, r0a + RB + HALF);
    const int ksb = (r0b - HALF) & ~31;
    const int keb = min(S_LEN, r0b + RB + HALF);
    const int qloa = r0a + WQ * wv_;
    const int qlob = r0b + WQ * wv_;

    // ---- Q fragments for BOTH tiles first (so their vmcnt wait precedes staging) ----
    bf16x8 qfa[2], qfb[2];
    #pragma unroll
    for (int ds = 0; ds < 2; ++ds) {
        const float* sa = Qg + (size_t)(qloa + cc) * DIM + ds * 32 + g * 8;
        const float* sb = Qg + (size_t)(qlob + cc) * DIM + ds * 32 + g * 8;
        float4 a = *(const float4*)sa, b = *(const float4*)(sa + 4);
        float4 c = *(const float4*)sb, d = *(const float4*)(sb + 4);
        a.x*=SCALE;a.y*=SCALE;a.z*=SCALE;a.w*=SCALE; b.x*=SCALE;b.y*=SCALE;b.z*=SCALE;b.w*=SCALE;
        c.x*=SCALE;c.y*=SCALE;c.z*=SCALE;c.w*=SCALE; d.x*=SCALE;d.y*=SCALE;d.z*=SCALE;d.w*=SCALE;
        qfa[ds] = cvt8(a, b);
        qfb[ds] = cvt8(c, d);
    }

    // ---- staging: K items 2048 (4/thread), V items 1024 (2/thread) ----
    float4 kr[4][2], vr[2][4];

    auto k_load = [&](int kstart, int kend) {
        #pragma unroll
        for (int i = 0; i < 4; ++i) {
            const int idx = u + i * THREADS;
            const int kg  = kstart + (idx >> 3);
            const int oct = idx & 7;
            if (kg < kend) {
                const float* p = Kg + (size_t)kg * DIM + oct * 8;
                kr[i][0] = *(const float4*)p; kr[i][1] = *(const float4*)(p + 4);
            } else {
                kr[i][0] = make_float4(0.f,0.f,0.f,0.f); kr[i][1] = kr[i][0];
            }
        }
    };
    auto k_write = [&](unsigned short* Kb) {
        #pragma unroll
        for (int i = 0; i < 4; ++i) {
            const int idx  = u + i * THREADS;
            const int krow = idx >> 3;
            const int oct  = idx & 7;
            *(uint4*)(Kb + krow * 64 + ((oct ^ (krow & 7)) << 3)) =
                __builtin_bit_cast(uint4, cvt8(kr[i][0], kr[i][1]));
        }
    };
    auto v_load = [&](int kstart, int kend) {
        #pragma unroll
        for (int i = 0; i < 2; ++i) {
            const int idx = u + i * THREADS;
            const int kg  = kstart + (idx >> 3) * 2;
            const int d0  = (idx & 7) * 8;
            if (kg < kend) {
                const float* p = Vg + (size_t)kg * DIM + d0;
                vr[i][0] = *(const float4*)p;         vr[i][1] = *(const float4*)(p + 4);
                vr[i][2] = *(const float4*)(p + DIM); vr[i][3] = *(const float4*)(p + DIM + 4);
            } else {
                vr[i][0] = make_float4(0.f,0.f,0.f,0.f);
                vr[i][1] = vr[i][0]; vr[i][2] = vr[i][0]; vr[i][3] = vr[i][0];
            }
        }
    };
    auto v_write = [&](unsigned short* Vb) {
        #pragma unroll
        for (int i = 0; i < 2; ++i) {
            const int idx = u + i * THREADS;
            const int k0  = (idx >> 3) * 2;
            const int m   = idx & 7;
            const float* a0 = (const float*)&vr[i][0];   // key k0,   8 dims
            const float* a1 = (const float*)&vr[i][2];   // key k0+1, 8 dims
            #pragma unroll
            for (int j = 0; j < 8; ++j) {                // static idx; banks split by ^m
                const int d  = m * 8 + j;
                const int sl = (k0 >> 3) ^ j ^ m;        // == (k0>>3)^(d&7)^((d>>3)&7)
                *(unsigned int*)(Vb + d * KCAP + sl * 8 + (k0 & 7)) = pk2(a0[j], a1[j]);
            }
        }
    };

    // ---- prologue: stage tile A ----
    k_load(ksa, kea); v_load(ksa, kea);
    k_write(Ks[0]);   v_write(Vs[0]);
    __syncthreads();

    // ---- issue tile B global loads; pin them above compute(A) ----
    k_load(ksb, keb); v_load(ksb, keb);
    __builtin_amdgcn_sched_barrier(0);

    // ---- compute tile A (hides tile-B load latency) ----
    unsigned short* Pw = Ps + wv_ * (16 * 40);
    attend_store(Ks[0], Vs[0], Pw, qfa, ksa, kea, qloa, g, cc, Og);

    // ---- convert + write tile B, then compute it ----
    k_write(Ks[1]); v_write(Vs[1]);
    __syncthreads();
    attend_store(Ks[1], Vs[1], Pw, qfb, ksb, keb, qlob, g, cc, Og);
}

extern "C" void kernel_launch(void* const* d_in, const int* in_sizes, int n_in,
                              void* d_out, int out_size, void* d_ws, size_t ws_size,
                              hipStream_t stream) {
    const float* q = (const float*)d_in[0];
    const float* k = (const float*)d_in[1];
    const float* v = (const float*)d_in[2];
    float* o = (float*)d_out;
    const int nbh = in_sizes[0] / (S_LEN * DIM);      // B*H = 16
    dim3 grid((S_LEN / (2 * RB)) * nbh);              // 256 blocks = 1/CU
    lattn_mfma<<<grid, THREADS, 0, stream>>>(q, k, v, o);
}

// Round 8
// 22.574 us; speedup vs baseline: 1.8930x; 1.8930x over previous
//
#include <hip/hip_runtime.h>

#define S_LEN 4096
#define DIM   64
#define HALF  50
#define RB    256           // query rows per block
#define WQ    16            // query rows per wave (16 waves)
#define THREADS 1024
#define KCAP  384           // staged keys: kstart = r0-64 (32-aligned), span <= 370
#define SCALE 0.125f

typedef __attribute__((ext_vector_type(8))) short bf16x8;
typedef __attribute__((ext_vector_type(4))) float f32x4;

__device__ __forceinline__ unsigned int bf16_rne(float f) {
    unsigned int u = __float_as_uint(f);
    return (u + 0x7fffu + ((u >> 16) & 1u)) >> 16;
}
__device__ __forceinline__ unsigned int pk2(float lo, float hi) {
    return bf16_rne(lo) | (bf16_rne(hi) << 16);
}
__device__ __forceinline__ bf16x8 cvt8(float4 a, float4 b) {
    uint4 t = make_uint4(pk2(a.x, a.y), pk2(a.z, a.w), pk2(b.x, b.y), pk2(b.z, b.w));
    return __builtin_bit_cast(bf16x8, t);
}

// LDS: K  [384 keys][64 d] bf16, slot' = slot ^ (key&7)                 (48KB)
//      V^T[64 d][384 keys] bf16, slot' = slot ^ (d&7) ^ ((d>>3)&7)      (48KB)
//      P  [16 waves][16 q][40 k] bf16 per-wave scratch                  (20KB)
// Staging = issue ALL global loads first (18 float4/thread in flight),
// sched_barrier, then pack+ds_write with counted vmcnt -> request-level MLP.
__global__ __launch_bounds__(THREADS, 4)
void lattn_mfma(const float* __restrict__ Q, const float* __restrict__ K,
                const float* __restrict__ V, float* __restrict__ O) {
    __shared__ unsigned short Ks[KCAP * 64];
    __shared__ unsigned short Vs[DIM * KCAP];
    __shared__ unsigned short Ps[16 * 16 * 40];

    // bijective XCD swizzle: consecutive r0-blocks (overlapping halos) share an XCD L2
    const int nwg = gridDim.x;                 // 256
    const int cpx = nwg >> 3;
    const int bid = blockIdx.x;
    const int logical = (bid & 7) * cpx + (bid >> 3);
    const int bh = logical >> 4;               // 16 x-blocks per bh
    const int r0 = (logical & 15) * RB;

    const size_t base = (size_t)bh * (S_LEN * DIM);
    const float* Qg = Q + base;
    const float* Kg = K + base;
    const float* Vg = V + base;
    float*       Og = O + base;

    const int kstart = (r0 >= HALF) ? ((r0 - HALF) & ~31) : 0;
    const int kend   = min(S_LEN, r0 + RB + HALF);         // exclusive

    const int u = threadIdx.x;
    const int lane = u & 63;
    const int wv_  = u >> 6;
    const int g  = lane >> 4;
    const int cc = lane & 15;
    const int qlo = r0 + WQ * wv_;

    // ================= STAGING: issue ALL loads, then pack =================
    float4 kA[3], kB[3];      // K: 3 items/thread (rows (u>>3)+i*128, oct u&7)
    float4 vA[2][4];          // V: 2 items/thread (key-pairs), 2nd only u<512
    float4 qA[2], qB[2];      // Q: 2x32B per lane

    #pragma unroll
    for (int i = 0; i < 3; ++i) {
        const int kg  = kstart + (u >> 3) + i * 128;
        const int oct = u & 7;
        if (kg < kend) {
            const float* p = Kg + (size_t)kg * DIM + oct * 8;
            kA[i] = *(const float4*)p; kB[i] = *(const float4*)(p + 4);
        } else {
            kA[i] = make_float4(0.f, 0.f, 0.f, 0.f); kB[i] = kA[i];
        }
    }
    #pragma unroll
    for (int i = 0; i < 2; ++i) {
        if (i == 0 || u < 512) {
            const int kg = kstart + (u >> 3) * 2 + i * 256;
            const int d0 = (u & 7) * 8;
            if (kg < kend) {
                const float* p = Vg + (size_t)kg * DIM + d0;
                vA[i][0] = *(const float4*)p;         vA[i][1] = *(const float4*)(p + 4);
                vA[i][2] = *(const float4*)(p + DIM); vA[i][3] = *(const float4*)(p + DIM + 4);
            } else {
                vA[i][0] = make_float4(0.f, 0.f, 0.f, 0.f);
                vA[i][1] = vA[i][0]; vA[i][2] = vA[i][0]; vA[i][3] = vA[i][0];
            }
        }
    }
    #pragma unroll
    for (int ds = 0; ds < 2; ++ds) {
        const float* src = Qg + (size_t)(qlo + cc) * DIM + ds * 32 + g * 8;
        qA[ds] = *(const float4*)src;
        qB[ds] = *(const float4*)(src + 4);
    }
    __builtin_amdgcn_sched_barrier(0);   // keep all load-issues above the packs

    // ---- pack + write K (retires kA/kB with counted vmcnt, V/Q stay in flight) ----
    #pragma unroll
    for (int i = 0; i < 3; ++i) {
        const int krow = (u >> 3) + i * 128;
        const int oct  = u & 7;
        *(uint4*)(Ks + krow * 64 + ((oct ^ (krow & 7)) << 3)) =
            __builtin_bit_cast(uint4, cvt8(kA[i], kB[i]));
    }
    // ---- pack + write V^T (static j; swizzle spreads the 8 sharers across banks) ----
    #pragma unroll
    for (int i = 0; i < 2; ++i) {
        if (i == 0 || u < 512) {
            const int k0 = (u >> 3) * 2 + i * 256;
            const int m  = u & 7;
            const float* a0 = (const float*)&vA[i][0];   // key k0,   dims m*8..+8
            const float* a1 = (const float*)&vA[i][2];   // key k0+1
            #pragma unroll
            for (int j = 0; j < 8; ++j) {
                const int d  = m * 8 + j;
                const int sl = (k0 >> 3) ^ j ^ m;        // == (k0>>3)^(d&7)^((d>>3)&7)
                *(unsigned int*)(Vs + d * KCAP + sl * 8 + (k0 & 7)) = pk2(a0[j], a1[j]);
            }
        }
    }
    // ---- pack Q fragments (scale folded) ----
    bf16x8 qf[2];
    #pragma unroll
    for (int ds = 0; ds < 2; ++ds) {
        float4 a = qA[ds], b = qB[ds];
        a.x*=SCALE; a.y*=SCALE; a.z*=SCALE; a.w*=SCALE;
        b.x*=SCALE; b.y*=SCALE; b.z*=SCALE; b.w*=SCALE;
        qf[ds] = cvt8(a, b);
    }

    __syncthreads();

    // ================= COMPUTE (round-3 verified inner loop) =================
    f32x4 oacc[4] = {};
    float denom = 0.f;

    int lo = (qlo >= HALF) ? (qlo - HALF) : 0;
    lo = max(kstart, lo & ~31);
    const int t0 = (lo - kstart) >> 5;
    const int hi = min(kend, qlo + WQ - 1 + HALF + 1);
    const int t1 = (hi - kstart + 31) >> 5;

    unsigned short* Pw = Ps + wv_ * (16 * 40);

    for (int st = t0; st < t1; ++st) {
        const int kb32 = st << 5;

        // swapped QK^T: S^T[key][q]
        f32x4 sacc[2] = {};
        #pragma unroll
        for (int ds = 0; ds < 2; ++ds) {
            #pragma unroll
            for (int kt = 0; kt < 2; ++kt) {
                const int krow = kb32 + kt * 16 + cc;
                const int sl   = (ds * 4 + g) ^ (krow & 7);
                const bf16x8 kfr = *(const bf16x8*)(Ks + krow * 64 + sl * 8);
                sacc[kt] = __builtin_amdgcn_mfma_f32_16x16x32_bf16(kfr, qf[ds], sacc[kt], 0, 0, 0);
            }
        }

        // mask + exp + P layout shuffle (per-wave LDS, wave-internal sync only)
        const int q = qlo + cc;
        #pragma unroll
        for (int kt = 0; kt < 2; ++kt) {
            float w4[4];
            const int keyb = kstart + kb32 + kt * 16 + g * 4;
            #pragma unroll
            for (int r = 0; r < 4; ++r) {
                const int key = keyb + r;
                const float e = __expf(fminf(sacc[kt][r], 60.f));
                const int dd  = key - q;
                const bool ok = (dd >= -HALF) && (dd <= HALF) && (key < S_LEN);
                w4[r] = ok ? e : 0.f;
                denom += w4[r];
            }
            *(uint2*)(Pw + cc * 40 + kt * 16 + g * 4) =
                make_uint2(pk2(w4[0], w4[1]), pk2(w4[2], w4[3]));
        }
        const bf16x8 pf = *(const bf16x8*)(Pw + cc * 40 + g * 8);

        // PV: O^T += V^T x P
        #pragma unroll
        for (int dt = 0; dt < 4; ++dt) {
            const int d  = dt * 16 + cc;
            const int sl = ((kb32 >> 3) + g) ^ (d & 7) ^ ((d >> 3) & 7);
            const bf16x8 vf = *(const bf16x8*)(Vs + d * KCAP + sl * 8);
            oacc[dt] = __builtin_amdgcn_mfma_f32_16x16x32_bf16(vf, pf, oacc[dt], 0, 0, 0);
        }
    }

    // ---- normalize + store ----
    denom += __shfl_xor(denom, 16);
    denom += __shfl_xor(denom, 32);
    const float rinv = 1.f / denom;
    float* dst = Og + (size_t)(qlo + cc) * DIM;
    #pragma unroll
    for (int dt = 0; dt < 4; ++dt) {
        const f32x4 o = oacc[dt];
        *(float4*)(dst + dt * 16 + g * 4) =
            make_float4(o[0] * rinv, o[1] * rinv, o[2] * rinv, o[3] * rinv);
    }
}

extern "C" void kernel_launch(void* const* d_in, const int* in_sizes, int n_in,
                              void* d_out, int out_size, void* d_ws, size_t ws_size,
                              hipStream_t stream) {
    const float* q = (const float*)d_in[0];
    const float* k = (const float*)d_in[1];
    const float* v = (const float*)d_in[2];
    float* o = (float*)d_out;
    const int nbh = in_sizes[0] / (S_LEN * DIM);      // B*H = 16
    dim3 grid((S_LEN / RB) * nbh);                    // 256 blocks = 1/CU
    lattn_mfma<<<grid, THREADS, 0, stream>>>(q, k, v, o);
}